// Round 4
// baseline (94.982 us; speedup 1.0000x reference)
//
#include <hip/hip_runtime.h>
#include <hip/hip_cooperative_groups.h>
#include <math.h>

namespace cg = cooperative_groups;

#define NBLK  64
#define NTHR  256
#define NB2   16384     // fine bins == n; same-bin => treated as tie (error ~1e-3 << 9.3e-2)
#define L2REG 0.01f

// ws layout (floats): fesum[NB2] | bsum[NBLK] | w2part[NBLK] | ppart[NBLK]
// One cooperative kernel, grid-wide phases, 5 grid syncs:
//   1. zero bins (thread-owned), load item, exp, W^2 block partials
//   2. histogram: atomicAdd(fesum[bin], e)
//   3. hierarchical inclusive-SUFFIX scan of fesum (wave shfl -> wave sums ->
//      block sums -> cross-block offsets), write back in place
//   4. risk[i] = fesum[bin_i]; cox block partials
//   5. block 0 reduces 64 partials, writes the scalar
__global__ void __launch_bounds__(NTHR)
cox_coop_kernel(const float* __restrict__ theta,
                const float* __restrict__ dur,
                const float* __restrict__ ev,
                const float* __restrict__ W,
                float* __restrict__ out,
                float* __restrict__ ws,
                int n, int wn) {
    cg::grid_group grid = cg::this_grid();

    float* fesum  = ws;            // [NB2]
    float* bsum   = ws + NB2;      // [NBLK]
    float* w2part = bsum + NBLK;   // [NBLK]
    float* ppart  = w2part + NBLK; // [NBLK]

    const int t    = threadIdx.x;
    const int b    = blockIdx.x;
    const int gid  = b * NTHR + t;          // item index == owned bin index
    const int lane = t & 63;
    const int wid  = t >> 6;

    __shared__ float sred[4];
    __shared__ float wsum[4];

    // ---------------- phase 1: zero own bin, load item, W^2 partial --------
    fesum[gid] = 0.f;

    float d = 0.f, e = 0.f, th = 0.f, evi = 0.f;
    if (gid < n) {
        d   = dur[gid];
        th  = theta[gid];
        evi = ev[gid];
        e   = expf(th);
    }

    float w2 = 0.f;
    for (int i = gid * 8; i < wn; i += NBLK * NTHR * 8) {  // exactly 1 iter at wn=131072
        float4 a = *reinterpret_cast<const float4*>(W + i);
        float4 c = *reinterpret_cast<const float4*>(W + i + 4);
        w2 += a.x*a.x + a.y*a.y + a.z*a.z + a.w*a.w
            + c.x*c.x + c.y*c.y + c.z*c.z + c.w*c.w;
    }
    #pragma unroll
    for (int off = 32; off > 0; off >>= 1) w2 += __shfl_down(w2, off, 64);
    if (lane == 0) sred[wid] = w2;
    __syncthreads();
    if (t == 0) w2part[b] = sred[0] + sred[1] + sred[2] + sred[3];

    __threadfence();
    grid.sync();                                            // A

    // ---------------- phase 2: fine histogram ------------------------------
    int fb = (int)(d * (float)NB2);
    fb = fb < 0 ? 0 : (fb >= NB2 ? NB2 - 1 : fb);
    if (gid < n) atomicAdd(&fesum[fb], e);

    __threadfence();
    grid.sync();                                            // B

    // ---------------- phase 3a: wave+block suffix partials -----------------
    float vs = fesum[gid];                  // own bin value
    #pragma unroll
    for (int off = 1; off < 64; off <<= 1) {
        float o = __shfl_down(vs, off, 64);
        vs += (lane + off < 64) ? o : 0.f;  // vs = sum of lanes [lane..63]
    }
    if (lane == 0) wsum[wid] = vs;          // wave total
    __syncthreads();
    float woff = 0.f;
    #pragma unroll
    for (int w = 0; w < 4; ++w)
        if (w > wid) woff += wsum[w];       // higher waves in this block
    if (t == 0) bsum[b] = wsum[0] + wsum[1] + wsum[2] + wsum[3];

    __threadfence();
    grid.sync();                                            // C

    // ---------------- phase 3b: cross-block offset, write back -------------
    float bv = (lane < NBLK && lane > b) ? bsum[lane] : 0.f;
    #pragma unroll
    for (int off = 32; off > 0; off >>= 1) bv += __shfl_xor(bv, off, 64);
    // bv = sum of bsum over blocks with index > b (all lanes)
    fesum[gid] = vs + woff + bv;            // inclusive suffix over all bins >= gid

    __threadfence();
    grid.sync();                                            // D

    // ---------------- phase 4: risk lookup + cox partial -------------------
    float p = 0.f;
    if (gid < n) {
        float risk = fesum[fb];             // includes own e (tie with self)
        p = (th - logf(risk)) * evi;
    }
    #pragma unroll
    for (int off = 32; off > 0; off >>= 1) p += __shfl_down(p, off, 64);
    __syncthreads();                        // sred reuse guard
    if (lane == 0) sred[wid] = p;
    __syncthreads();
    if (t == 0) ppart[b] = sred[0] + sred[1] + sred[2] + sred[3];

    __threadfence();
    grid.sync();                                            // E

    // ---------------- phase 5: finalize ------------------------------------
    if (b == 0 && t == 0) {
        float ps = 0.f, wsq = 0.f;
        #pragma unroll 8
        for (int k = 0; k < NBLK; ++k) { ps += ppart[k]; wsq += w2part[k]; }
        out[0] = -ps / (float)n + L2REG * sqrtf(wsq);
    }
}

extern "C" void kernel_launch(void* const* d_in, const int* in_sizes, int n_in,
                              void* d_out, int out_size, void* d_ws, size_t ws_size,
                              hipStream_t stream) {
    const float* hazard = (const float*)d_in[0];  // [n,1]
    const float* dur    = (const float*)d_in[1];  // [n]
    const float* ev     = (const float*)d_in[2];  // [n]
    const float* W      = (const float*)d_in[3];  // [512*256]
    int n  = in_sizes[1];                          // 16384
    int wn = in_sizes[3];                          // 131072

    float* out = (float*)d_out;
    float* ws  = (float*)d_ws;

    void* args[] = { (void*)&hazard, (void*)&dur, (void*)&ev, (void*)&W,
                     (void*)&out, (void*)&ws, (void*)&n, (void*)&wn };

    hipLaunchCooperativeKernel((const void*)cox_coop_kernel,
                               dim3(NBLK), dim3(NTHR),
                               args, 0, stream);
}

// Round 5
// 37.028 us; speedup vs baseline: 2.5652x; 2.5652x over previous
//
#include <hip/hip_runtime.h>
#include <math.h>

#define K1B   128
#define K1T   256
#define NT2   1024
#define NB2   16384          // fine bins; same-bin => tie (validated: absmax 0.0 in R4)
#define IT2   (NB2 / NT2)    // 16 items/bins per thread in K2
#define L2REG 0.01f

// ---------------------------------------------------------------------------
// K1 (whole GPU): e[j] = exp(theta[j]); w2part[b] = block partial of sum(W^2)
// ---------------------------------------------------------------------------
__global__ void __launch_bounds__(K1T)
prep_kernel(const float* __restrict__ theta,
            const float* __restrict__ W,
            float* __restrict__ e,
            float* __restrict__ w2part,
            int n, int wn) {
    int gid = blockIdx.x * K1T + threadIdx.x;
    int stride = K1B * K1T;

    for (int j = gid; j < n; j += stride)
        e[j] = expf(theta[j]);

    float w2 = 0.f;
    for (int i = gid * 4; i < wn; i += stride * 4) {   // exactly 1 float4/thread at wn=131072
        float4 w = *reinterpret_cast<const float4*>(W + i);
        w2 += w.x * w.x + w.y * w.y + w.z * w.z + w.w * w.w;
    }
    #pragma unroll
    for (int off = 32; off > 0; off >>= 1)
        w2 += __shfl_down(w2, off, 64);

    __shared__ float sred[4];
    if ((threadIdx.x & 63) == 0) sred[threadIdx.x >> 6] = w2;
    __syncthreads();
    if (threadIdx.x == 0)
        w2part[blockIdx.x] = sred[0] + sred[1] + sred[2] + sred[3];
}

// ---------------------------------------------------------------------------
// K2 (single WG, 1024 threads): LDS histogram -> in-LDS suffix scan ->
// risk lookup + cox reduce + W^2 total -> scalar out. No global scratch init.
// ---------------------------------------------------------------------------
__global__ void __launch_bounds__(NT2)
fuse_kernel(const float* __restrict__ theta,
            const float* __restrict__ dur,
            const float* __restrict__ ev,
            const float* __restrict__ e,
            const float* __restrict__ w2part,
            float* __restrict__ out,
            int n) {
    __shared__ float fesum[NB2];     // 64 KB
    __shared__ float wtot[16];
    __shared__ float red[32];

    const int t = threadIdx.x, lane = t & 63, wid = t >> 6;

    // zero own 16 bins (contiguous chunk, b128 stores)
    float4* f4 = reinterpret_cast<float4*>(fesum);
    #pragma unroll
    for (int k = 0; k < 4; ++k)
        f4[t * 4 + k] = make_float4(0.f, 0.f, 0.f, 0.f);
    __syncthreads();

    // histogram: item j's exp into its fine bin (LDS atomics, random bins)
    int bin[IT2];
    #pragma unroll
    for (int it = 0; it < IT2; ++it) {
        int j = t + it * NT2;
        float dj = 0.f, ej = 0.f;
        if (j < n) { dj = dur[j]; ej = e[j]; }
        int bx = (int)(dj * (float)NB2);
        bx = bx < 0 ? 0 : (bx >= NB2 ? NB2 - 1 : bx);
        bin[it] = bx;
        if (j < n) atomicAdd(&fesum[bx], ej);
    }
    __syncthreads();

    // inclusive SUFFIX scan of fesum. Thread owns bins [t*16, t*16+16).
    float v[IT2];
    float run = 0.f;
    #pragma unroll
    for (int k = IT2 - 1; k >= 0; --k) {    // own-chunk serial suffix
        run += fesum[t * IT2 + k];
        v[k] = run;
    }
    // wave-level inclusive suffix of chunk totals (lanes hi->lo)
    float wsfx = run;
    #pragma unroll
    for (int off = 1; off < 64; off <<= 1) {
        float o = __shfl_down(wsfx, off, 64);
        if (lane + off < 64) wsfx += o;
    }
    if (lane == 0) wtot[wid] = wsfx;        // whole-wave total
    __syncthreads();
    float woff = 0.f;
    #pragma unroll
    for (int w = 0; w < 16; ++w)
        if (w > wid) woff += wtot[w];       // totals of higher waves
    float off0 = (wsfx - run) + woff;       // excl suffix of higher threads
    #pragma unroll
    for (int k = 0; k < IT2; ++k) v[k] += off0;
    // own-chunk writeback (no cross-thread hazard: reads/writes own chunk only)
    #pragma unroll
    for (int k = 0; k < IT2; ++k) fesum[t * IT2 + k] = v[k];
    __syncthreads();

    // risk lookup + cox partial
    float p = 0.f;
    #pragma unroll
    for (int it = 0; it < IT2; ++it) {
        int j = t + it * NT2;
        if (j < n)
            p += (theta[j] - logf(fesum[bin[it]])) * ev[j];
    }

    // reduce cox partial and W^2 partials
    float w2 = (t < K1B) ? w2part[t] : 0.f;
    #pragma unroll
    for (int off = 32; off > 0; off >>= 1) {
        p  += __shfl_down(p,  off, 64);
        w2 += __shfl_down(w2, off, 64);
    }
    if (lane == 0) { red[wid] = p; red[wid + 16] = w2; }
    __syncthreads();
    if (t == 0) {
        float ps = 0.f, wsq = 0.f;
        #pragma unroll
        for (int k = 0; k < 16; ++k) { ps += red[k]; wsq += red[k + 16]; }
        out[0] = -ps / (float)n + L2REG * sqrtf(wsq);
    }
}

extern "C" void kernel_launch(void* const* d_in, const int* in_sizes, int n_in,
                              void* d_out, int out_size, void* d_ws, size_t ws_size,
                              hipStream_t stream) {
    const float* hazard = (const float*)d_in[0];  // [n,1]
    const float* dur    = (const float*)d_in[1];  // [n]
    const float* ev     = (const float*)d_in[2];  // [n]
    const float* W      = (const float*)d_in[3];  // [512*256]
    int n  = in_sizes[1];                          // 16384
    int wn = in_sizes[3];                          // 131072

    float* e      = (float*)d_ws;        // [n]
    float* w2part = e + NB2;             // [K1B]

    prep_kernel<<<K1B, K1T, 0, stream>>>(hazard, W, e, w2part, n, wn);
    fuse_kernel<<<1, NT2, 0, stream>>>(hazard, dur, ev, e, w2part,
                                       (float*)d_out, n);
}

// Round 6
// 16.530 us; speedup vs baseline: 5.7462x; 2.2401x over previous
//
#include <hip/hip_runtime.h>
#include <math.h>

#define PB    16        // blocks in K1 (slabs)
#define N2B   16        // blocks in K2
#define NT    1024      // threads per block
#define NBIN  4096      // bins; same-bin => tie (err ~1e-4, threshold 9.3e-2)
#define L2REG 0.01f

__device__ __forceinline__ int bin_of(float d) {
    int b = (int)(d * (float)NBIN);
    return b < 0 ? 0 : (b >= NBIN ? NBIN - 1 : b);
}

// ---------------------------------------------------------------------------
// K1: per-block PRIVATE 4096-bin LDS histogram of exp(theta) (no global
// atomics -> no zero-init), full-slab plain store; W^2 block partials;
// block 0 zeroes acc + ticket for K2.
// ---------------------------------------------------------------------------
__global__ void __launch_bounds__(NT)
prep_kernel(const float* __restrict__ theta,
            const float* __restrict__ dur,
            const float* __restrict__ W,
            float* __restrict__ slab,      // [PB][NBIN]
            float* __restrict__ w2part,    // [PB]
            float* __restrict__ acc,       // [2]
            int* __restrict__ ticket,
            int n, int wn) {
    __shared__ float hist[NBIN];
    __shared__ float sred[16];
    const int t = threadIdx.x, b = blockIdx.x;
    const int lane = t & 63, wid = t >> 6;

    #pragma unroll
    for (int k = 0; k < NBIN / NT; ++k)
        hist[t + k * NT] = 0.f;
    __syncthreads();

    for (int j = b * NT + t; j < n; j += PB * NT) {
        float dj = dur[j];
        float ej = expf(theta[j]);
        atomicAdd(&hist[bin_of(dj)], ej);        // LDS atomic, private
    }

    float w2 = 0.f;
    for (int i = (b * NT + t) * 8; i < wn; i += PB * NT * 8) {
        float4 a = *reinterpret_cast<const float4*>(W + i);
        float4 c = *reinterpret_cast<const float4*>(W + i + 4);
        w2 += a.x*a.x + a.y*a.y + a.z*a.z + a.w*a.w
            + c.x*c.x + c.y*c.y + c.z*c.z + c.w*c.w;
    }
    #pragma unroll
    for (int off = 32; off > 0; off >>= 1) w2 += __shfl_down(w2, off, 64);
    if (lane == 0) sred[wid] = w2;
    __syncthreads();
    if (t == 0) {
        float s = 0.f;
        #pragma unroll
        for (int k = 0; k < NT / 64; ++k) s += sred[k];
        w2part[b] = s;
        if (b == 0) { acc[0] = 0.f; acc[1] = 0.f; *ticket = 0; }
    }

    // store full slab (plain coalesced stores; every slot written)
    #pragma unroll
    for (int k = 0; k < NBIN / NT; ++k)
        slab[b * NBIN + t + k * NT] = hist[t + k * NT];
}

// ---------------------------------------------------------------------------
// K2: per-block redundant slab-reduce into LDS -> in-LDS inclusive suffix
// scan of 4096 bins -> risk lookup + cox partial -> atomicAdd; last block
// (atomic ticket) finalizes scalar. No extra node.
// ---------------------------------------------------------------------------
__global__ void __launch_bounds__(NT)
fuse_kernel(const float* __restrict__ theta,
            const float* __restrict__ dur,
            const float* __restrict__ ev,
            const float* __restrict__ slab,
            const float* __restrict__ w2part,
            float* __restrict__ acc,
            int* __restrict__ ticket,
            float* __restrict__ out,
            int n) {
    __shared__ float fes[NBIN];
    __shared__ float wtot[16];
    __shared__ float red[16];
    const int t = threadIdx.x, b = blockIdx.x;
    const int lane = t & 63, wid = t >> 6;
    const int C = NBIN / NT;                    // 4 bins/thread

    // reduce 16 slabs (coalesced: consecutive threads -> consecutive bins)
    float s[C];
    #pragma unroll
    for (int k = 0; k < C; ++k) s[k] = 0.f;
    for (int sl = 0; sl < PB; ++sl) {
        const float* sp = slab + sl * NBIN;
        #pragma unroll
        for (int k = 0; k < C; ++k) s[k] += sp[t + k * NT];
    }
    #pragma unroll
    for (int k = 0; k < C; ++k) fes[t + k * NT] = s[k];
    __syncthreads();

    // inclusive suffix scan; thread owns contiguous bins [t*C, t*C+C)
    float v[C];
    float run = 0.f;
    #pragma unroll
    for (int k = C - 1; k >= 0; --k) {
        run += fes[t * C + k];
        v[k] = run;
    }
    float wsfx = run;                           // wave suffix of chunk totals
    #pragma unroll
    for (int off = 1; off < 64; off <<= 1) {
        float o = __shfl_down(wsfx, off, 64);
        if (lane + off < 64) wsfx += o;
    }
    if (lane == 0) wtot[wid] = wsfx;
    __syncthreads();
    float woff = 0.f;
    #pragma unroll
    for (int w = 0; w < NT / 64; ++w)
        if (w > wid) woff += wtot[w];
    float off0 = (wsfx - run) + woff;           // excl suffix of higher threads
    #pragma unroll
    for (int k = 0; k < C; ++k) fes[t * C + k] = v[k] + off0;   // own chunk only
    __syncthreads();

    // risk lookup + cox partial (1 item/thread at n=16384)
    float p = 0.f;
    for (int j = b * NT + t; j < n; j += N2B * NT) {
        float r = fes[bin_of(dur[j])];          // inclusive suffix => ties incl self
        p += (theta[j] - logf(r)) * ev[j];
    }
    #pragma unroll
    for (int off = 32; off > 0; off >>= 1) p += __shfl_down(p, off, 64);
    if (lane == 0) red[wid] = p;
    __syncthreads();
    if (t == 0) {
        float ps = 0.f;
        #pragma unroll
        for (int k = 0; k < NT / 64; ++k) ps += red[k];
        atomicAdd(&acc[0], ps);
        __threadfence();
        int tk = atomicAdd(ticket, 1);
        if (tk == N2B - 1) {                    // last block finalizes
            float cox = atomicAdd(&acc[0], 0.f);   // coherent read
            float w2 = 0.f;
            #pragma unroll
            for (int k = 0; k < PB; ++k) w2 += w2part[k];
            out[0] = -cox / (float)n + L2REG * sqrtf(w2);
        }
    }
}

extern "C" void kernel_launch(void* const* d_in, const int* in_sizes, int n_in,
                              void* d_out, int out_size, void* d_ws, size_t ws_size,
                              hipStream_t stream) {
    const float* hazard = (const float*)d_in[0];  // [n,1]
    const float* dur    = (const float*)d_in[1];  // [n]
    const float* ev     = (const float*)d_in[2];  // [n]
    const float* W      = (const float*)d_in[3];  // [512*256]
    int n  = in_sizes[1];                          // 16384
    int wn = in_sizes[3];                          // 131072

    float* slab   = (float*)d_ws;          // [PB*NBIN]
    float* w2part = slab + PB * NBIN;      // [PB]
    float* acc    = w2part + PB;           // [2]
    int*   ticket = (int*)(acc + 2);       // [1]

    prep_kernel<<<PB, NT, 0, stream>>>(hazard, dur, W, slab, w2part,
                                       acc, ticket, n, wn);
    fuse_kernel<<<N2B, NT, 0, stream>>>(hazard, dur, ev, slab, w2part,
                                        acc, ticket, (float*)d_out, n);
}